// Round 6
// baseline (317.971 us; speedup 1.0000x reference)
//
#include <hip/hip_runtime.h>
#include <hip/hip_bf16.h>
#include <hip/hip_fp16.h>

#define SEQ    2048
#define DMODEL 2048
#define NH     16
#define NKV    4
#define HD     128
#define NTOT   3072   // DMODEL + 2*NKV*HD
#define MROWS  4096   // B*SEQ

typedef __attribute__((ext_vector_type(4))) float f32x4;
typedef __attribute__((ext_vector_type(8))) __bf16 bf16x8;
typedef __attribute__((ext_vector_type(8))) unsigned short u16x8;
typedef __attribute__((ext_vector_type(4))) unsigned short u16x4;

__device__ __forceinline__ void async_copy16(const void* g, void* l) {
  __builtin_amdgcn_global_load_lds(
      (const __attribute__((address_space(1))) void*)g,
      (__attribute__((address_space(3))) void*)l, 16, 0, 0);
}

__device__ __forceinline__ unsigned short fto16(float f) {
  __hip_bfloat16 h = __float2bfloat16(f);
  return *(unsigned short*)&h;
}

__device__ __forceinline__ float b2f(unsigned short u) {
  unsigned int t = (unsigned int)u << 16;
  float f;
  __builtin_memcpy(&f, &t, 4);
  return f;
}

// ---------------- fake-quant (all 4 weights in one launch) ----------------
__global__ __launch_bounds__(256) void fq_kernel(const float* __restrict__ Wq,
                                                 const float* __restrict__ Wk,
                                                 const float* __restrict__ Wv,
                                                 const float* __restrict__ Wp,
                                                 unsigned short* __restrict__ Wcat,
                                                 unsigned short* __restrict__ Wpq) {
  int g = blockIdx.x * 4 + (threadIdx.x >> 6);
  int lane = threadIdx.x & 63;
  const float* W;
  unsigned short* out;
  int blk;
  if (g < 32768)      { W = Wq; out = Wcat;                          blk = g; }
  else if (g < 40960) { W = Wk; out = Wcat + (size_t)2048 * 2048;    blk = g - 32768; }
  else if (g < 49152) { W = Wv; out = Wcat + (size_t)2560 * 2048;    blk = g - 40960; }
  else                { W = Wp; out = Wpq;                           blk = g - 49152; }
  const float* p = W + (size_t)blk * 128 + lane * 2;
  float w0 = p[0], w1 = p[1];
  float m = fmaxf(fabsf(w0), fabsf(w1));
#pragma unroll
  for (int o = 32; o; o >>= 1) m = fmaxf(m, __shfl_xor(m, o));
  float s = fmaxf(m / 31.0f, 1e-12f);
  s = __half2float(__float2half(s));        // fp16 RNE round of scale
  s = fmaxf(s, 6.103515625e-05f);           // fp16 tiny
  float q0 = rintf(fminf(fmaxf(w0 / s, -32.0f), 31.0f)) * s;
  float q1 = rintf(fminf(fmaxf(w1 / s, -32.0f), 31.0f)) * s;
  unsigned short* o16 = out + (size_t)blk * 128 + lane * 2;
  o16[0] = fto16(q0);
  o16[1] = fto16(q1);
}

// ---------------- fp32 -> bf16 convert ----------------
__global__ __launch_bounds__(256) void conv_kernel(const float* __restrict__ in,
                                                   unsigned short* __restrict__ out,
                                                   int n) {
  int i = (blockIdx.x * blockDim.x + threadIdx.x) * 4;
  if (i >= n) return;
  float4 v = *(const float4*)(in + i);
  ushort4 o;
  o.x = fto16(v.x); o.y = fto16(v.y); o.z = fto16(v.z); o.w = fto16(v.w);
  *(ushort4*)(out + i) = o;
}

// ---------------- bf16 MFMA GEMM, 256x256 tile, counted-vmcnt pipeline -------
// m201-template port: BM=BN=256, BK=64, 512 thr / 8 waves (2M x 4N), 128x64
// output per wave, LDS 128KB (2 x (A 256x64 + B 256x64) bf16 double-buffer).
// One raw s_barrier per K-tile; all 8 global_load_lds for tile t+1 issued right
// after it; then s_waitcnt vmcnt(8) = "all of tile t retired" (in-order), which
// is ~free since tile t's loads had the whole previous compute phase to land.
// NEVER vmcnt(0) in the main loop (T4 - the measured +38-73% lever, m218).
// Rule-21 involution swizzle (pre-swizzled global src granule, XOR on read);
// B-frags register-cached across the 4 MFMA quadrants (24 ds_read_b128 / 64
// MFMA); setprio around MFMA clusters (T5); XCD-bijective block swizzle (T1).
#define BM 256
#define BN 256
#define BK 64
template <typename OT>
__global__ __launch_bounds__(512, 1) void gemm_bt(const unsigned short* __restrict__ A,
                                                  const unsigned short* __restrict__ Bm,
                                                  OT* __restrict__ C,
                                                  int M, int N, int K) {
  __shared__ unsigned short S[2][2][16384];   // [buf][A/B][256*64] = 128 KB
  const int tid = threadIdx.x;
  const int wave = tid >> 6, lane = tid & 63;
  const int quad = lane >> 4, l16 = lane & 15;

  // XCD bijective swizzle (nwg % 8 == 0 for both launches: 192, 128)
  int wg = blockIdx.y * gridDim.x + blockIdx.x;
  int nwg = gridDim.x * gridDim.y;
  int cpx = nwg >> 3;
  int swz = (wg & 7) * cpx + (wg >> 3);
  int bxs = swz % gridDim.x, bys = swz / gridDim.x;
  const int m0 = bxs * BM, n0 = bys * BN;
  const int wm = (wave >> 2) * 128;           // 2 M-wave groups
  const int wn = (wave & 3) * 64;             // 4 N-wave groups

  const unsigned short* Ag = A + (size_t)m0 * K;
  const unsigned short* Bg = Bm + (size_t)n0 * K;

  f32x4 acc[8][4];
#pragma unroll
  for (int i = 0; i < 8; i++)
#pragma unroll
    for (int j = 0; j < 4; j++) acc[i][j] = f32x4{0.f, 0.f, 0.f, 0.f};

  // staging: round c covers rows c*64 + wave*8 + (lane>>3); granule pre-swizzled
  // gsrc = (lane&7) ^ (row&7) with row&7 == lane>>3 (c*64, wave*8 are mult of 8).
  const int srow = wave * 8 + (lane >> 3);
  const int sg8 = ((lane & 7) ^ (lane >> 3)) * 8;
  const unsigned short* gA = Ag + (size_t)srow * K + sg8;
  const unsigned short* gB = Bg + (size_t)srow * K + sg8;
  const int ldsw = wave * 512;                // wave-uniform; HW scatters lane*16B

#define STAGE(t, b)                                                             \
  {                                                                             \
    _Pragma("unroll") for (int c_ = 0; c_ < 4; ++c_)                            \
        async_copy16(gA + (size_t)c_ * 64 * K + (t) * BK, &S[(b)][0][c_ * 4096 + ldsw]); \
    _Pragma("unroll") for (int c_ = 0; c_ < 4; ++c_)                            \
        async_copy16(gB + (size_t)c_ * 64 * K + (t) * BK, &S[(b)][1][c_ * 4096 + ldsw]); \
  }

  const int nt = K >> 6;                      // 32 K-tiles
  STAGE(0, 0);                                // prologue: tile 0 in flight

#pragma unroll 1
  for (int t = 0; t < nt; ++t) {
    __asm__ volatile("s_barrier" ::: "memory");   // all waves done reading buf[(t+1)&1]
    if (t + 1 < nt) {
      STAGE(t + 1, (t + 1) & 1);                  // 8 loads for t+1, fly across compute(t)
      __asm__ volatile("s_waitcnt vmcnt(8)" ::: "memory");  // tile t fully landed
    } else {
      __asm__ volatile("s_waitcnt vmcnt(0)" ::: "memory");  // last tile: drain
    }
    __builtin_amdgcn_sched_barrier(0);

    const unsigned short* As = &S[t & 1][0][0];
    const unsigned short* Bs = &S[t & 1][1][0];

    bf16x8 bf[4][2];                          // B-frags cached for all quadrants
#pragma unroll
    for (int j = 0; j < 4; ++j)
#pragma unroll
      for (int kk = 0; kk < 2; ++kk)
        bf[j][kk] = *(const bf16x8*)&Bs[(wn + j * 16 + l16) * 64 + ((((kk << 2) + quad) ^ (l16 & 7)) << 3)];

#pragma unroll
    for (int q = 0; q < 4; ++q) {             // 4 C-quadrants (m-frag pairs)
      bf16x8 af[2][2];
#pragma unroll
      for (int i2 = 0; i2 < 2; ++i2)
#pragma unroll
        for (int kk = 0; kk < 2; ++kk)
          af[i2][kk] = *(const bf16x8*)&As[(wm + (q * 2 + i2) * 16 + l16) * 64 + ((((kk << 2) + quad) ^ (l16 & 7)) << 3)];
      __builtin_amdgcn_s_setprio(1);
#pragma unroll
      for (int i2 = 0; i2 < 2; ++i2)
#pragma unroll
        for (int j = 0; j < 4; ++j)
#pragma unroll
          for (int kk = 0; kk < 2; ++kk)
            acc[q * 2 + i2][j] = __builtin_amdgcn_mfma_f32_16x16x32_bf16(af[i2][kk], bf[j][kk], acc[q * 2 + i2][j], 0, 0, 0);
      __builtin_amdgcn_s_setprio(0);
    }
  }
#undef STAGE

#pragma unroll
  for (int i = 0; i < 8; i++) {
    int row_base = m0 + wm + i * 16 + quad * 4;
#pragma unroll
    for (int j = 0; j < 4; j++) {
      int col = n0 + wn + j * 16 + l16;
#pragma unroll
      for (int r = 0; r < 4; r++) {
        if constexpr (sizeof(OT) == 2)
          C[(size_t)(row_base + r) * N + col] = fto16(acc[i][j][r]);
        else
          C[(size_t)(row_base + r) * N + col] = acc[i][j][r];
      }
    }
  }
}

// ---------------- RMSNorm + RoPE + gain (Q,K only), bf16 in/out ----------------
#define QSCALE 0.12751791437524245f   // (1/sqrt(128)) * log2(e)
__global__ __launch_bounds__(256) void normrope_kernel(const unsigned short* __restrict__ qkvb,
                                                       const float* __restrict__ qgain,
                                                       unsigned short* __restrict__ qbuf,
                                                       unsigned short* __restrict__ kbuf) {
  const int i = blockIdx.x;            // token 0..4095
  const int bz = i >> 11, tok = i & 2047;
  const int wave = threadIdx.x >> 6, lane = threadIdx.x & 63;
  const unsigned short* row = qkvb + (size_t)i * NTOT;

  double invf = pow(10000.0, -(double)(2 * lane) / 128.0);
  float freq = (float)((double)tok * invf);
  float cs = cosf(freq), sn = sinf(freq);

  for (int slot = wave; slot < 20; slot += 4) {
    if (slot < 16) {                   // q heads: norm + rope + gain*scale
      int hh = slot;
      const unsigned short* src = row + hh * HD;
      float x1 = b2f(src[lane]), x2 = b2f(src[lane + 64]);
      float ss = x1 * x1 + x2 * x2;
#pragma unroll
      for (int o = 32; o; o >>= 1) ss += __shfl_xor(ss, o);
      float rn = rsqrtf(ss * (1.0f / 128.0f) + 1.1920929e-07f);
      float n1 = x1 * rn, n2 = x2 * rn;
      float g = qgain[hh] * QSCALE;
      unsigned short* dst = qbuf + ((size_t)(bz * NH + hh) * SEQ + tok) * HD;
      dst[lane]      = fto16((n1 * cs + n2 * sn) * g);
      dst[lane + 64] = fto16((-n1 * sn + n2 * cs) * g);
    } else {                           // k heads: norm + rope
      int hh = slot - 16;
      const unsigned short* src = row + DMODEL + hh * HD;
      float x1 = b2f(src[lane]), x2 = b2f(src[lane + 64]);
      float ss = x1 * x1 + x2 * x2;
#pragma unroll
      for (int o = 32; o; o >>= 1) ss += __shfl_xor(ss, o);
      float rn = rsqrtf(ss * (1.0f / 128.0f) + 1.1920929e-07f);
      float n1 = x1 * rn, n2 = x2 * rn;
      unsigned short* dst = kbuf + ((size_t)(bz * NKV + hh) * SEQ + tok) * HD;
      dst[lane]      = fto16(n1 * cs + n2 * sn);
      dst[lane + 64] = fto16(-n1 * sn + n2 * cs);
    }
  }
}

// ---------------- V transpose: bf16 qkv v-section -> bf16 V^T [b,kvh,d,s] ----------------
__global__ __launch_bounds__(256) void vtrans_kernel(const unsigned short* __restrict__ qkvb,
                                                     unsigned short* __restrict__ vtb) {
  __shared__ unsigned short T[64 * 72];
  const int s0 = blockIdx.x * 64;
  const int d0 = blockIdx.y * 64;
  const int bz = blockIdx.z >> 2, h = blockIdx.z & 3;
  const int tid = threadIdx.x;
#pragma unroll
  for (int i = 0; i < 2; ++i) {
    int c = i * 256 + tid;
    int s = c >> 3, ch = c & 7;
    const unsigned short* src =
        qkvb + (size_t)(bz * SEQ + s0 + s) * NTOT + DMODEL + 512 + h * HD + d0 + ch * 8;
    *(u16x8*)&T[s * 72 + ch * 8] = *(const u16x8*)src;
  }
  __syncthreads();
  unsigned short* outg = vtb + (size_t)(bz * NKV + h) * HD * SEQ;
#pragma unroll
  for (int i = 0; i < 2; ++i) {
    int c = i * 256 + tid;
    int d = c >> 3, sc = c & 7;
    u16x8 v;
#pragma unroll
    for (int j = 0; j < 8; ++j) v[j] = T[(sc * 8 + j) * 72 + d];
    *(u16x8*)(outg + (size_t)(d0 + d) * SEQ + s0 + sc * 8) = v;
  }
}

// ---------------- flash attention (round-3 version, best measured: 77.4us) ----
// 128-row Q tile, 8 waves (16 rows/wave). K: dbuf direct global_load_lds
// (pre-swizzled global source, linear LDS dest - rule-21 involution); K(kt+1)
// issued between barriers A and B, in flight across compute(kt), drained by the
// next iteration's __syncthreads. V: reg-prefetch + swizzled ds_write.
__global__ __launch_bounds__(512, 4) void attn_kernel(const unsigned short* __restrict__ qb,
                                                      const unsigned short* __restrict__ kb,
                                                      const unsigned short* __restrict__ vtb,
                                                      unsigned short* __restrict__ yb) {
  __shared__ unsigned short Ks[2][64 * 128];  // 32 KB (dbuf)
  __shared__ unsigned short Vt[128 * 64];     // 16 KB
  __shared__ unsigned short Ps[8][16 * 64];   // 16 KB   -> 64 KB total

  const int bx = blockIdx.x;
  const int h = blockIdx.y;
  const int bz = blockIdx.z;
  const int qt = bz ? bx : (15 - bx);     // bz-pairing: CU partner gets 15-qt
  const int tid = threadIdx.x;
  const int wave = tid >> 6, lane = tid & 63;
  const int quad = lane >> 4, l16 = lane & 15;
  const int q0 = qt * 128;
  const int base = q0 + wave * 16;        // this wave's 16-row group
  const int kdiag = base >> 6;

  const unsigned short* qg = qb + (size_t)(bz * NH + h) * SEQ * HD;
  const unsigned short* kg = kb + (size_t)(bz * NKV + (h >> 2)) * SEQ * HD;
  const unsigned short* vg = vtb + (size_t)(bz * NKV + (h >> 2)) * HD * SEQ;
  unsigned short* psw = &Ps[wave][0];

  bf16x8 qf[4];
#pragma unroll
  for (int ds = 0; ds < 4; ++ds)
    qf[ds] = *(const bf16x8*)(qg + (size_t)(base + l16) * HD + ds * 32 + quad * 8);

  f32x4 oacc[8];
#pragma unroll
  for (int j = 0; j < 8; ++j) oacc[j] = f32x4{0.f, 0.f, 0.f, 0.f};
  float m_i = -__builtin_inff();
  float l_i = 0.f;

  const int krow0 = wave * 4 + (lane >> 4);
  const int ksrcg = (lane & 15) ^ (krow0 & 15);
  const unsigned short* kgK = kg + (size_t)krow0 * HD + ksrcg * 8;

  const int vdw = tid >> 3, vgr = tid & 7;    // 64 d/iter, 8 granules/row

  const int nkt = 2 * qt + 2;

  // prologue: stage K(0) direct, prefetch V(0) to regs
  async_copy16(kgK, &Ks[0][wave * 512]);
  async_copy16(kgK + (size_t)32 * HD, &Ks[0][4096 + wave * 512]);
  u16x8 pv[2];
#pragma unroll
  for (int i = 0; i < 2; ++i)
    pv[i] = *(const u16x8*)(vg + (size_t)(i * 64 + vdw) * SEQ + vgr * 8);

  for (int kt = 0; kt < nkt; ++kt) {
    // (A) full drain + barrier: prev LDS reads done, K(kt) DMA landed, pv(kt) ready
    __syncthreads();
#pragma unroll
    for (int i = 0; i < 2; ++i) {
      int d = i * 64 + vdw;
      *(u16x8*)&Vt[d * 64 + ((vgr ^ (d & 7)) << 3)] = pv[i];
    }
    if (kt + 1 < nkt) {                  // stage K(kt+1): flies across compute(kt)
      const unsigned short* s = kgK + (size_t)(kt + 1) * 64 * HD;
      async_copy16(s, &Ks[(kt + 1) & 1][wave * 512]);
      async_copy16(s + (size_t)32 * HD, &Ks[(kt + 1) & 1][4096 + wave * 512]);
    }
    __asm__ volatile("s_waitcnt lgkmcnt(0)" ::: "memory");  // my V writes visible
    __builtin_amdgcn_sched_barrier(0);
    __asm__ volatile("s_barrier" ::: "memory");  // (B) V staged; K(kt+1) in flight

    if (kt + 1 < nkt) {                  // prefetch V(kt+1) into regs
#pragma unroll
      for (int i = 0; i < 2; ++i)
        pv[i] = *(const u16x8*)(vg + (size_t)(i * 64 + vdw) * SEQ + (kt + 1) * 64 + vgr * 8);
    }

    if (kt <= kdiag) {
      const unsigned short* Kc = Ks[kt & 1];
      f32x4 st[4];
#pragma unroll
      for (int mt = 0; mt < 4; ++mt) st[mt] = f32x4{0.f, 0.f, 0.f, 0.f};
      __builtin_amdgcn_s_setprio(1);
#pragma unroll
      for (int mt = 0; mt < 4; ++mt)
#pragma unroll
        for (int ds = 0; ds < 4; ++ds) {
          bf16x8 kf = *(const bf16x8*)&Kc[(mt * 16 + l16) * 128 + ((((ds << 2) + quad) ^ l16) << 3)];
          st[mt] = __builtin_amdgcn_mfma_f32_16x16x32_bf16(kf, qf[ds], st[mt], 0, 0, 0);
        }
      __builtin_amdgcn_s_setprio(0);

      const int qrow = base + l16;
      float p[4][4];
      float mx = -__builtin_inff();
      if (kt == kdiag) {                 // diagonal tile: causal mask
#pragma unroll
        for (int mt = 0; mt < 4; ++mt)
#pragma unroll
          for (int r = 0; r < 4; ++r) {
            int kp = kt * 64 + mt * 16 + quad * 4 + r;
            float v = (kp <= qrow) ? st[mt][r] : -__builtin_inff();
            p[mt][r] = v;
            mx = fmaxf(mx, v);
          }
      } else {
#pragma unroll
        for (int mt = 0; mt < 4; ++mt)
#pragma unroll
          for (int r = 0; r < 4; ++r) {
            p[mt][r] = st[mt][r];
            mx = fmaxf(mx, st[mt][r]);
          }
      }
      mx = fmaxf(mx, __shfl_xor(mx, 16));
      mx = fmaxf(mx, __shfl_xor(mx, 32));
      float mnew = (mx > m_i + 8.f) ? mx : m_i;   // defer-max THR=8
      float rs = 0.f;
#pragma unroll
      for (int mt = 0; mt < 4; ++mt)
#pragma unroll
        for (int r = 0; r < 4; ++r) {
          float e = exp2f(p[mt][r] - mnew);
          p[mt][r] = e;
          rs += e;
        }
      rs += __shfl_xor(rs, 16);
      rs += __shfl_xor(rs, 32);
      if (mnew != m_i) {                 // rescale only when deferred max moved
        float a = exp2f(m_i - mnew);
#pragma unroll
        for (int j = 0; j < 8; ++j) oacc[j] *= a;
        l_i = l_i * a + rs;
        m_i = mnew;
      } else {
        l_i += rs;
      }

#pragma unroll
      for (int mt = 0; mt < 4; ++mt) {
        u16x4 w;
#pragma unroll
        for (int r = 0; r < 4; ++r) w[r] = fto16(p[mt][r]);
        int g = mt * 2 + (quad >> 1);
        *(u16x4*)&psw[l16 * 64 + ((g ^ (l16 & 7)) << 3) + (quad & 1) * 4] = w;
      }

      __asm__ volatile("s_waitcnt lgkmcnt(0)" ::: "memory");  // own P writes -> reads

      __builtin_amdgcn_s_setprio(1);
#pragma unroll
      for (int c = 0; c < 2; ++c) {
        bf16x8 pf = *(const bf16x8*)&psw[l16 * 64 + ((((c << 2) + quad) ^ (l16 & 7)) << 3)];
#pragma unroll
        for (int mt = 0; mt < 8; ++mt) {
          bf16x8 vf = *(const bf16x8*)&Vt[(mt * 16 + l16) * 64 + ((((c << 2) + quad) ^ (l16 & 7)) << 3)];
          oacc[mt] = __builtin_amdgcn_mfma_f32_16x16x32_bf16(vf, pf, oacc[mt], 0, 0, 0);
        }
      }
      __builtin_amdgcn_s_setprio(0);
    }
  }

  // epilogue: O^T row = d = mt*16+quad*4+r, col = q = l16; per-lane invl
  {
    float il = 1.0f / l_i;
    int qrow = base + l16;
#pragma unroll
    for (int mt = 0; mt < 8; ++mt) {
      u16x4 o;
#pragma unroll
      for (int r = 0; r < 4; ++r) o[r] = fto16(oacc[mt][r] * il);
      *(u16x4*)&yb[(size_t)(bz * SEQ + qrow) * DMODEL + h * HD + mt * 16 + quad * 4] = o;
    }
  }
}

extern "C" void kernel_launch(void* const* d_in, const int* in_sizes, int n_in,
                              void* d_out, int out_size, void* d_ws, size_t ws_size,
                              hipStream_t stream) {
  (void)in_sizes; (void)n_in; (void)out_size; (void)ws_size;
  const float* x  = (const float*)d_in[0];
  const float* Wq = (const float*)d_in[1];
  const float* Wk = (const float*)d_in[2];
  const float* Wv = (const float*)d_in[3];
  const float* Wp = (const float*)d_in[4];
  const float* qg = (const float*)d_in[5];
  float* out = (float*)d_out;
  char* ws = (char*)d_ws;

  // workspace layout; yb aliases xb (x consumed by GEMM1 before attn writes y)
  unsigned short* xb   = (unsigned short*)(ws + 0);          // 16.78 MB
  unsigned short* Wcat = (unsigned short*)(ws + 16777216);   // 12.58 MB (Wq|Wk|Wv rows)
  unsigned short* Wpq  = (unsigned short*)(ws + 29360128);   // 8.39 MB
  unsigned short* qkvb = (unsigned short*)(ws + 37748736);   // 25.17 MB (bf16 qkv)
  unsigned short* qbuf = (unsigned short*)(ws + 62914560);   // 16.78 MB
  unsigned short* kbuf = (unsigned short*)(ws + 79691776);   // 4.19 MB
  unsigned short* vtb  = (unsigned short*)(ws + 83886080);   // 4.19 MB (V^T)
  unsigned short* yb   = xb;

  fq_kernel<<<81920 / 4, 256, 0, stream>>>(Wq, Wk, Wv, Wp, Wcat, Wpq);
  conv_kernel<<<8388608 / 1024, 256, 0, stream>>>(x, xb, 8388608);
  gemm_bt<unsigned short><<<dim3(16, 12), 512, 0, stream>>>(xb, Wcat, qkvb, MROWS, NTOT, DMODEL);
  normrope_kernel<<<MROWS, 256, 0, stream>>>(qkvb, qg, qbuf, kbuf);
  vtrans_kernel<<<dim3(32, 2, 8), 256, 0, stream>>>(qkvb, vtb);
  attn_kernel<<<dim3(16, NH, 2), 512, 0, stream>>>(qbuf, kbuf, vtb, yb);
  gemm_bt<float><<<dim3(16, 8), 512, 0, stream>>>(yb, Wpq, out, MROWS, DMODEL, DMODEL);
}

// Round 7
// 302.256 us; speedup vs baseline: 1.0520x; 1.0520x over previous
//
#include <hip/hip_runtime.h>
#include <hip/hip_bf16.h>
#include <hip/hip_fp16.h>

#define SEQ    2048
#define DMODEL 2048
#define NH     16
#define NKV    4
#define HD     128
#define NTOT   3072   // DMODEL + 2*NKV*HD
#define MROWS  4096   // B*SEQ

typedef __attribute__((ext_vector_type(4))) float f32x4;
typedef __attribute__((ext_vector_type(8))) __bf16 bf16x8;
typedef __attribute__((ext_vector_type(8))) unsigned short u16x8;
typedef __attribute__((ext_vector_type(4))) unsigned short u16x4;

__device__ __forceinline__ void async_copy16(const void* g, void* l) {
  __builtin_amdgcn_global_load_lds(
      (const __attribute__((address_space(1))) void*)g,
      (__attribute__((address_space(3))) void*)l, 16, 0, 0);
}

__device__ __forceinline__ unsigned short fto16(float f) {
  __hip_bfloat16 h = __float2bfloat16(f);
  return *(unsigned short*)&h;
}

__device__ __forceinline__ float b2f(unsigned short u) {
  unsigned int t = (unsigned int)u << 16;
  float f;
  __builtin_memcpy(&f, &t, 4);
  return f;
}

// ---------------- fake-quant (all 4 weights in one launch) ----------------
__global__ __launch_bounds__(256) void fq_kernel(const float* __restrict__ Wq,
                                                 const float* __restrict__ Wk,
                                                 const float* __restrict__ Wv,
                                                 const float* __restrict__ Wp,
                                                 unsigned short* __restrict__ Wcat,
                                                 unsigned short* __restrict__ Wpq) {
  int g = blockIdx.x * 4 + (threadIdx.x >> 6);
  int lane = threadIdx.x & 63;
  const float* W;
  unsigned short* out;
  int blk;
  if (g < 32768)      { W = Wq; out = Wcat;                          blk = g; }
  else if (g < 40960) { W = Wk; out = Wcat + (size_t)2048 * 2048;    blk = g - 32768; }
  else if (g < 49152) { W = Wv; out = Wcat + (size_t)2560 * 2048;    blk = g - 40960; }
  else                { W = Wp; out = Wpq;                           blk = g - 49152; }
  const float* p = W + (size_t)blk * 128 + lane * 2;
  float w0 = p[0], w1 = p[1];
  float m = fmaxf(fabsf(w0), fabsf(w1));
#pragma unroll
  for (int o = 32; o; o >>= 1) m = fmaxf(m, __shfl_xor(m, o));
  float s = fmaxf(m / 31.0f, 1e-12f);
  s = __half2float(__float2half(s));        // fp16 RNE round of scale
  s = fmaxf(s, 6.103515625e-05f);           // fp16 tiny
  float q0 = rintf(fminf(fmaxf(w0 / s, -32.0f), 31.0f)) * s;
  float q1 = rintf(fminf(fmaxf(w1 / s, -32.0f), 31.0f)) * s;
  unsigned short* o16 = out + (size_t)blk * 128 + lane * 2;
  o16[0] = fto16(q0);
  o16[1] = fto16(q1);
}

// ---------------- fp32 -> bf16 convert ----------------
__global__ __launch_bounds__(256) void conv_kernel(const float* __restrict__ in,
                                                   unsigned short* __restrict__ out,
                                                   int n) {
  int i = (blockIdx.x * blockDim.x + threadIdx.x) * 4;
  if (i >= n) return;
  float4 v = *(const float4*)(in + i);
  ushort4 o;
  o.x = fto16(v.x); o.y = fto16(v.y); o.z = fto16(v.z); o.w = fto16(v.w);
  *(ushort4*)(out + i) = o;
}

// ---------------- bf16 MFMA GEMM, C[m,n] = sum_k A[m,k]*B[n,k] ----------------
// R3-proven config: BK=64 (halves barrier drains vs BK=32); rule-21 involution
// swizzle (linear LDS dest for global_load_lds, pre-swizzled GLOBAL granule,
// XOR on read); XCD bijective block swizzle.
// V^T fusion: when vtb != nullptr, block-cols with n0 >= 2560 (the V section of
// the qkv GEMM; block-uniform since 2560 % BN == 0) are stored TRANSPOSED
// directly to vtb[b,kvh,d,s] — replaces the vtrans kernel entirely.
#define BM 128
#define BN 128
#define BK 64
template <typename OT>
__global__ __launch_bounds__(256, 3) void gemm_bt(const unsigned short* __restrict__ A,
                                                  const unsigned short* __restrict__ Bm,
                                                  OT* __restrict__ C,
                                                  unsigned short* __restrict__ vtb,
                                                  int M, int N, int K) {
  __shared__ unsigned short As[BM * BK];   // 16 KB
  __shared__ unsigned short Bs[BN * BK];   // 16 KB
  const int tid = threadIdx.x;
  const int wave = tid >> 6, lane = tid & 63;
  const int quad = lane >> 4, l16 = lane & 15;

  // XCD bijective swizzle (nwg % 8 == 0 for both launches: 768, 512)
  int wg = blockIdx.y * gridDim.x + blockIdx.x;
  int nwg = gridDim.x * gridDim.y;
  int cpx = nwg >> 3;
  int swz = (wg & 7) * cpx + (wg >> 3);
  int bxs = swz % gridDim.x, bys = swz / gridDim.x;
  const int m0 = bxs * BM, n0 = bys * BN;
  const int wm = (wave >> 1) * 64, wn = (wave & 1) * 64;

  const unsigned short* Ag = A + (size_t)m0 * K;
  const unsigned short* Bg = Bm + (size_t)n0 * K;

  f32x4 acc[4][4];
#pragma unroll
  for (int i = 0; i < 4; i++)
#pragma unroll
    for (int j = 0; j < 4; j++) acc[i][j] = f32x4{0.f, 0.f, 0.f, 0.f};

  // staging: copy c stages rows c*32..c*32+31; thread covers row tid>>3.
  // Source granule pre-swizzled: (lane&7) ^ (row&7), row&7 == lane>>3 (uniform in c,wave).
  const int srow = tid >> 3;
  const int sg8 = (((lane & 7) ^ (lane >> 3))) * 8;
  const unsigned short* gA = Ag + (size_t)srow * K + sg8;
  const unsigned short* gB = Bg + (size_t)srow * K + sg8;
  unsigned short* lA = &As[wave * 512];    // wave-uniform; HW scatters lane*16B
  unsigned short* lB = &Bs[wave * 512];

  for (int k0 = 0; k0 < K; k0 += BK) {
    __syncthreads();
#pragma unroll
    for (int c = 0; c < 4; ++c) async_copy16(gA + (size_t)c * 32 * K + k0, lA + c * 2048);
#pragma unroll
    for (int c = 0; c < 4; ++c) async_copy16(gB + (size_t)c * 32 * K + k0, lB + c * 2048);
    __syncthreads();
#pragma unroll
    for (int kk = 0; kk < 2; ++kk) {
      bf16x8 af[4], bf[4];
#pragma unroll
      for (int t = 0; t < 4; t++)
        af[t] = *(const bf16x8*)&As[(wm + t * 16 + l16) * BK + ((((kk << 2) + quad) ^ (l16 & 7)) << 3)];
#pragma unroll
      for (int t = 0; t < 4; t++)
        bf[t] = *(const bf16x8*)&Bs[(wn + t * 16 + l16) * BK + ((((kk << 2) + quad) ^ (l16 & 7)) << 3)];
#pragma unroll
      for (int i = 0; i < 4; i++)
#pragma unroll
        for (int j = 0; j < 4; j++)
          acc[i][j] = __builtin_amdgcn_mfma_f32_16x16x32_bf16(af[i], bf[j], acc[i][j], 0, 0, 0);
    }
  }

  const bool isv = (vtb != nullptr) && (n0 >= 2560);   // V block-cols (block-uniform)
  if (isv) {
    // transposed store: vtb[((bz*4 + kvh)*128 + d) * 2048 + s], 4 s-consecutive/lane
    const int kvh = (n0 - 2560) >> 7;
#pragma unroll
    for (int i = 0; i < 4; i++) {
      int row0 = m0 + wm + i * 16 + quad * 4;      // 4 consecutive tokens
      int bz = row0 >> 11, s0 = row0 & 2047;       // 128-row tile never crosses bz
#pragma unroll
      for (int j = 0; j < 4; j++) {
        int d = wn + j * 16 + l16;                 // head-dim index 0..127
        u16x4 o;
#pragma unroll
        for (int r = 0; r < 4; r++) o[r] = fto16(acc[i][j][r]);
        *(u16x4*)&vtb[(size_t)((bz * NKV + kvh) * HD + d) * SEQ + s0] = o;
      }
    }
    return;
  }
#pragma unroll
  for (int i = 0; i < 4; i++) {
    int row_base = m0 + wm + i * 16 + quad * 4;
#pragma unroll
    for (int j = 0; j < 4; j++) {
      int col = n0 + wn + j * 16 + l16;
#pragma unroll
      for (int r = 0; r < 4; r++) {
        if constexpr (sizeof(OT) == 2)
          C[(size_t)(row_base + r) * N + col] = fto16(acc[i][j][r]);
        else
          C[(size_t)(row_base + r) * N + col] = acc[i][j][r];
      }
    }
  }
}

// ---------------- RMSNorm + RoPE + gain (Q,K only), bf16 in/out ----------------
// inv_freq in f32 via exp2f (matches the reference's f32 computation mode);
// the old per-thread DOUBLE pow() was a multi-hundred-cycle softfloat sequence.
#define QSCALE 0.12751791437524245f   // (1/sqrt(128)) * log2(e)
#define NEG_L2RB_64 (-0.2076205059304601f)   // -log2(10000)/64
__global__ __launch_bounds__(256) void normrope_kernel(const unsigned short* __restrict__ qkvb,
                                                       const float* __restrict__ qgain,
                                                       unsigned short* __restrict__ qbuf,
                                                       unsigned short* __restrict__ kbuf) {
  const int i = blockIdx.x;            // token 0..4095
  const int bz = i >> 11, tok = i & 2047;
  const int wave = threadIdx.x >> 6, lane = threadIdx.x & 63;
  const unsigned short* row = qkvb + (size_t)i * NTOT;

  float invf = exp2f((float)lane * NEG_L2RB_64);   // 10000^(-2*lane/128)
  float freq = (float)tok * invf;
  float cs = cosf(freq), sn = sinf(freq);

  for (int slot = wave; slot < 20; slot += 4) {
    if (slot < 16) {                   // q heads: norm + rope + gain*scale
      int hh = slot;
      const unsigned short* src = row + hh * HD;
      float x1 = b2f(src[lane]), x2 = b2f(src[lane + 64]);
      float ss = x1 * x1 + x2 * x2;
#pragma unroll
      for (int o = 32; o; o >>= 1) ss += __shfl_xor(ss, o);
      float rn = rsqrtf(ss * (1.0f / 128.0f) + 1.1920929e-07f);
      float n1 = x1 * rn, n2 = x2 * rn;
      float g = qgain[hh] * QSCALE;
      unsigned short* dst = qbuf + ((size_t)(bz * NH + hh) * SEQ + tok) * HD;
      dst[lane]      = fto16((n1 * cs + n2 * sn) * g);
      dst[lane + 64] = fto16((-n1 * sn + n2 * cs) * g);
    } else {                           // k heads: norm + rope
      int hh = slot - 16;
      const unsigned short* src = row + DMODEL + hh * HD;
      float x1 = b2f(src[lane]), x2 = b2f(src[lane + 64]);
      float ss = x1 * x1 + x2 * x2;
#pragma unroll
      for (int o = 32; o; o >>= 1) ss += __shfl_xor(ss, o);
      float rn = rsqrtf(ss * (1.0f / 128.0f) + 1.1920929e-07f);
      float n1 = x1 * rn, n2 = x2 * rn;
      unsigned short* dst = kbuf + ((size_t)(bz * NKV + hh) * SEQ + tok) * HD;
      dst[lane]      = fto16(n1 * cs + n2 * sn);
      dst[lane + 64] = fto16(-n1 * sn + n2 * cs);
    }
  }
}

// ---------------- flash attention (R3/R6 version, best measured: 73.7us) ----
// 128-row Q tile, 8 waves (16 rows/wave). K: dbuf direct global_load_lds
// (pre-swizzled global source, linear LDS dest - rule-21 involution); K(kt+1)
// issued between barriers A and B, in flight across compute(kt), drained by the
// next iteration's __syncthreads. V: reg-prefetch + swizzled ds_write.
__global__ __launch_bounds__(512, 4) void attn_kernel(const unsigned short* __restrict__ qb,
                                                      const unsigned short* __restrict__ kb,
                                                      const unsigned short* __restrict__ vtb,
                                                      unsigned short* __restrict__ yb) {
  __shared__ unsigned short Ks[2][64 * 128];  // 32 KB (dbuf)
  __shared__ unsigned short Vt[128 * 64];     // 16 KB
  __shared__ unsigned short Ps[8][16 * 64];   // 16 KB   -> 64 KB total

  const int bx = blockIdx.x;
  const int h = blockIdx.y;
  const int bz = blockIdx.z;
  const int qt = bz ? bx : (15 - bx);     // bz-pairing: CU partner gets 15-qt
  const int tid = threadIdx.x;
  const int wave = tid >> 6, lane = tid & 63;
  const int quad = lane >> 4, l16 = lane & 15;
  const int q0 = qt * 128;
  const int base = q0 + wave * 16;        // this wave's 16-row group
  const int kdiag = base >> 6;

  const unsigned short* qg = qb + (size_t)(bz * NH + h) * SEQ * HD;
  const unsigned short* kg = kb + (size_t)(bz * NKV + (h >> 2)) * SEQ * HD;
  const unsigned short* vg = vtb + (size_t)(bz * NKV + (h >> 2)) * HD * SEQ;
  unsigned short* psw = &Ps[wave][0];

  bf16x8 qf[4];
#pragma unroll
  for (int ds = 0; ds < 4; ++ds)
    qf[ds] = *(const bf16x8*)(qg + (size_t)(base + l16) * HD + ds * 32 + quad * 8);

  f32x4 oacc[8];
#pragma unroll
  for (int j = 0; j < 8; ++j) oacc[j] = f32x4{0.f, 0.f, 0.f, 0.f};
  float m_i = -__builtin_inff();
  float l_i = 0.f;

  const int krow0 = wave * 4 + (lane >> 4);
  const int ksrcg = (lane & 15) ^ (krow0 & 15);
  const unsigned short* kgK = kg + (size_t)krow0 * HD + ksrcg * 8;

  const int vdw = tid >> 3, vgr = tid & 7;    // 64 d/iter, 8 granules/row

  const int nkt = 2 * qt + 2;

  // prologue: stage K(0) direct, prefetch V(0) to regs
  async_copy16(kgK, &Ks[0][wave * 512]);
  async_copy16(kgK + (size_t)32 * HD, &Ks[0][4096 + wave * 512]);
  u16x8 pv[2];
#pragma unroll
  for (int i = 0; i < 2; ++i)
    pv[i] = *(const u16x8*)(vg + (size_t)(i * 64 + vdw) * SEQ + vgr * 8);

  for (int kt = 0; kt < nkt; ++kt) {
    // (A) full drain + barrier: prev LDS reads done, K(kt) DMA landed, pv(kt) ready
    __syncthreads();
#pragma unroll
    for (int i = 0; i < 2; ++i) {
      int d = i * 64 + vdw;
      *(u16x8*)&Vt[d * 64 + ((vgr ^ (d & 7)) << 3)] = pv[i];
    }
    if (kt + 1 < nkt) {                  // stage K(kt+1): flies across compute(kt)
      const unsigned short* s = kgK + (size_t)(kt + 1) * 64 * HD;
      async_copy16(s, &Ks[(kt + 1) & 1][wave * 512]);
      async_copy16(s + (size_t)32 * HD, &Ks[(kt + 1) & 1][4096 + wave * 512]);
    }
    __asm__ volatile("s_waitcnt lgkmcnt(0)" ::: "memory");  // my V writes visible
    __builtin_amdgcn_sched_barrier(0);
    __asm__ volatile("s_barrier" ::: "memory");  // (B) V staged; K(kt+1) in flight

    if (kt + 1 < nkt) {                  // prefetch V(kt+1) into regs
#pragma unroll
      for (int i = 0; i < 2; ++i)
        pv[i] = *(const u16x8*)(vg + (size_t)(i * 64 + vdw) * SEQ + (kt + 1) * 64 + vgr * 8);
    }

    if (kt <= kdiag) {
      const unsigned short* Kc = Ks[kt & 1];
      f32x4 st[4];
#pragma unroll
      for (int mt = 0; mt < 4; ++mt) st[mt] = f32x4{0.f, 0.f, 0.f, 0.f};
      __builtin_amdgcn_s_setprio(1);
#pragma unroll
      for (int mt = 0; mt < 4; ++mt)
#pragma unroll
        for (int ds = 0; ds < 4; ++ds) {
          bf16x8 kf = *(const bf16x8*)&Kc[(mt * 16 + l16) * 128 + ((((ds << 2) + quad) ^ l16) << 3)];
          st[mt] = __builtin_amdgcn_mfma_f32_16x16x32_bf16(kf, qf[ds], st[mt], 0, 0, 0);
        }
      __builtin_amdgcn_s_setprio(0);

      const int qrow = base + l16;
      float p[4][4];
      float mx = -__builtin_inff();
      if (kt == kdiag) {                 // diagonal tile: causal mask
#pragma unroll
        for (int mt = 0; mt < 4; ++mt)
#pragma unroll
          for (int r = 0; r < 4; ++r) {
            int kp = kt * 64 + mt * 16 + quad * 4 + r;
            float v = (kp <= qrow) ? st[mt][r] : -__builtin_inff();
            p[mt][r] = v;
            mx = fmaxf(mx, v);
          }
      } else {
#pragma unroll
        for (int mt = 0; mt < 4; ++mt)
#pragma unroll
          for (int r = 0; r < 4; ++r) {
            p[mt][r] = st[mt][r];
            mx = fmaxf(mx, st[mt][r]);
          }
      }
      mx = fmaxf(mx, __shfl_xor(mx, 16));
      mx = fmaxf(mx, __shfl_xor(mx, 32));
      float mnew = (mx > m_i + 8.f) ? mx : m_i;   // defer-max THR=8
      float rs = 0.f;
#pragma unroll
      for (int mt = 0; mt < 4; ++mt)
#pragma unroll
        for (int r = 0; r < 4; ++r) {
          float e = exp2f(p[mt][r] - mnew);
          p[mt][r] = e;
          rs += e;
        }
      rs += __shfl_xor(rs, 16);
      rs += __shfl_xor(rs, 32);
      if (mnew != m_i) {                 // rescale only when deferred max moved
        float a = exp2f(m_i - mnew);
#pragma unroll
        for (int j = 0; j < 8; ++j) oacc[j] *= a;
        l_i = l_i * a + rs;
        m_i = mnew;
      } else {
        l_i += rs;
      }

#pragma unroll
      for (int mt = 0; mt < 4; ++mt) {
        u16x4 w;
#pragma unroll
        for (int r = 0; r < 4; ++r) w[r] = fto16(p[mt][r]);
        int g = mt * 2 + (quad >> 1);
        *(u16x4*)&psw[l16 * 64 + ((g ^ (l16 & 7)) << 3) + (quad & 1) * 4] = w;
      }

      __asm__ volatile("s_waitcnt lgkmcnt(0)" ::: "memory");  // own P writes -> reads

      __builtin_amdgcn_s_setprio(1);
#pragma unroll
      for (int c = 0; c < 2; ++c) {
        bf16x8 pf = *(const bf16x8*)&psw[l16 * 64 + ((((c << 2) + quad) ^ (l16 & 7)) << 3)];
#pragma unroll
        for (int mt = 0; mt < 8; ++mt) {
          bf16x8 vf = *(const bf16x8*)&Vt[(mt * 16 + l16) * 64 + ((((c << 2) + quad) ^ (l16 & 7)) << 3)];
          oacc[mt] = __builtin_amdgcn_mfma_f32_16x16x32_bf16(vf, pf, oacc[mt], 0, 0, 0);
        }
      }
      __builtin_amdgcn_s_setprio(0);
    }
  }

  // epilogue: O^T row = d = mt*16+quad*4+r, col = q = l16; per-lane invl
  {
    float il = 1.0f / l_i;
    int qrow = base + l16;
#pragma unroll
    for (int mt = 0; mt < 8; ++mt) {
      u16x4 o;
#pragma unroll
      for (int r = 0; r < 4; ++r) o[r] = fto16(oacc[mt][r] * il);
      *(u16x4*)&yb[(size_t)(bz * SEQ + qrow) * DMODEL + h * HD + mt * 16 + quad * 4] = o;
    }
  }
}

extern "C" void kernel_launch(void* const* d_in, const int* in_sizes, int n_in,
                              void* d_out, int out_size, void* d_ws, size_t ws_size,
                              hipStream_t stream) {
  (void)in_sizes; (void)n_in; (void)out_size; (void)ws_size;
  const float* x  = (const float*)d_in[0];
  const float* Wq = (const float*)d_in[1];
  const float* Wk = (const float*)d_in[2];
  const float* Wv = (const float*)d_in[3];
  const float* Wp = (const float*)d_in[4];
  const float* qg = (const float*)d_in[5];
  float* out = (float*)d_out;
  char* ws = (char*)d_ws;

  // workspace layout; yb aliases xb (x consumed by GEMM1 before attn writes y)
  unsigned short* xb   = (unsigned short*)(ws + 0);          // 16.78 MB
  unsigned short* Wcat = (unsigned short*)(ws + 16777216);   // 12.58 MB (Wq|Wk|Wv rows)
  unsigned short* Wpq  = (unsigned short*)(ws + 29360128);   // 8.39 MB
  unsigned short* qkvb = (unsigned short*)(ws + 37748736);   // 25.17 MB (bf16 qkv)
  unsigned short* qbuf = (unsigned short*)(ws + 62914560);   // 16.78 MB
  unsigned short* kbuf = (unsigned short*)(ws + 79691776);   // 4.19 MB
  unsigned short* vtb  = (unsigned short*)(ws + 83886080);   // 4.19 MB (V^T)
  unsigned short* yb   = xb;

  fq_kernel<<<81920 / 4, 256, 0, stream>>>(Wq, Wk, Wv, Wp, Wcat, Wpq);
  conv_kernel<<<8388608 / 1024, 256, 0, stream>>>(x, xb, 8388608);
  // gemm1 writes Q,K to qkvb and V TRANSPOSED straight to vtb (vtrans fused)
  gemm_bt<unsigned short><<<dim3(32, 24), 256, 0, stream>>>(xb, Wcat, qkvb, vtb, MROWS, NTOT, DMODEL);
  normrope_kernel<<<MROWS, 256, 0, stream>>>(qkvb, qg, qbuf, kbuf);
  attn_kernel<<<dim3(16, NH, 2), 512, 0, stream>>>(qbuf, kbuf, vtb, yb);
  gemm_bt<float><<<dim3(32, 16), 256, 0, stream>>>(yb, Wpq, out, nullptr, MROWS, DMODEL, DMODEL);
}

// Round 8
// 292.177 us; speedup vs baseline: 1.0883x; 1.0345x over previous
//
#include <hip/hip_runtime.h>
#include <hip/hip_bf16.h>
#include <hip/hip_fp16.h>

#define SEQ    2048
#define DMODEL 2048
#define NH     16
#define NKV    4
#define HD     128
#define NTOT   3072   // DMODEL + 2*NKV*HD
#define MROWS  4096   // B*SEQ

typedef __attribute__((ext_vector_type(4))) float f32x4;
typedef __attribute__((ext_vector_type(8))) __bf16 bf16x8;
typedef __attribute__((ext_vector_type(8))) unsigned short u16x8;
typedef __attribute__((ext_vector_type(4))) unsigned short u16x4;

__device__ __forceinline__ void async_copy16(const void* g, void* l) {
  __builtin_amdgcn_global_load_lds(
      (const __attribute__((address_space(1))) void*)g,
      (__attribute__((address_space(3))) void*)l, 16, 0, 0);
}

__device__ __forceinline__ unsigned short fto16(float f) {
  __hip_bfloat16 h = __float2bfloat16(f);
  return *(unsigned short*)&h;
}

__device__ __forceinline__ float b2f(unsigned short u) {
  unsigned int t = (unsigned int)u << 16;
  float f;
  __builtin_memcpy(&f, &t, 4);
  return f;
}

#define QSCALE 0.12751791437524245f          // (1/sqrt(128)) * log2(e)
#define NEG_L2RB_64 (-0.2076205059304601f)   // -log2(10000)/64

// ---------------- prep: fake-quant + fp32->bf16 convert + rope tables --------
// One launch, block-range dispatch (all branches block-uniform).
#define NFQ   20480        // fq: 81920 groups / 4 per block
#define NCONV 8192         // conv: 8388608 elems / 1024 per block
#define NROPE 512          // rope: 131072 entries / 256 per block
__global__ __launch_bounds__(256) void prep_kernel(const float* __restrict__ Wq,
                                                   const float* __restrict__ Wk,
                                                   const float* __restrict__ Wv,
                                                   const float* __restrict__ Wp,
                                                   const float* __restrict__ x,
                                                   unsigned short* __restrict__ Wcat,
                                                   unsigned short* __restrict__ Wpq,
                                                   unsigned short* __restrict__ xb,
                                                   float* __restrict__ CS,
                                                   float* __restrict__ SN) {
  const int bid = blockIdx.x;
  const int tid = threadIdx.x;
  if (bid < NFQ) {                     // ---- fake-quant ----
    int g = bid * 4 + (tid >> 6);
    int lane = tid & 63;
    const float* W;
    unsigned short* out;
    int blk;
    if (g < 32768)      { W = Wq; out = Wcat;                          blk = g; }
    else if (g < 40960) { W = Wk; out = Wcat + (size_t)2048 * 2048;    blk = g - 32768; }
    else if (g < 49152) { W = Wv; out = Wcat + (size_t)2560 * 2048;    blk = g - 40960; }
    else                { W = Wp; out = Wpq;                           blk = g - 49152; }
    const float* p = W + (size_t)blk * 128 + lane * 2;
    float w0 = p[0], w1 = p[1];
    float m = fmaxf(fabsf(w0), fabsf(w1));
#pragma unroll
    for (int o = 32; o; o >>= 1) m = fmaxf(m, __shfl_xor(m, o));
    float s = fmaxf(m / 31.0f, 1e-12f);
    s = __half2float(__float2half(s));      // fp16 RNE round of scale
    s = fmaxf(s, 6.103515625e-05f);         // fp16 tiny
    float q0 = rintf(fminf(fmaxf(w0 / s, -32.0f), 31.0f)) * s;
    float q1 = rintf(fminf(fmaxf(w1 / s, -32.0f), 31.0f)) * s;
    unsigned short* o16 = out + (size_t)blk * 128 + lane * 2;
    o16[0] = fto16(q0);
    o16[1] = fto16(q1);
  } else if (bid < NFQ + NCONV) {      // ---- x fp32 -> bf16 ----
    int i = ((bid - NFQ) * 256 + tid) * 4;
    float4 v = *(const float4*)(x + i);
    ushort4 o;
    o.x = fto16(v.x); o.y = fto16(v.y); o.z = fto16(v.z); o.w = fto16(v.w);
    *(ushort4*)(xb + i) = o;
  } else {                             // ---- rope cos/sin tables ----
    int idx = (bid - NFQ - NCONV) * 256 + tid;   // 0..131071
    int t = idx >> 6, l = idx & 63;
    float invf = exp2f((float)l * NEG_L2RB_64);  // 10000^(-2l/128)
    float fr = (float)t * invf;
    CS[idx] = cosf(fr);
    SN[idx] = sinf(fr);
  }
}

// ---------------- bf16 MFMA GEMM, C[m,n] = sum_k A[m,k]*B[n,k] ----------------
// R3-proven config: BK=64; rule-21 involution swizzle (linear LDS dest for
// global_load_lds, pre-swizzled GLOBAL granule, XOR on read); XCD bijective
// block swizzle.
// FUSED epilogues (gemm1 only; all block-uniform on n0):
//   n0 >= 2560 : V section -> store TRANSPOSED to vtb[b,kvh,d,s]  (was vtrans)
//   n0 <  2560 : Q/K section -> RMSNorm + RoPE + gain via LDS re-stage, store
//                straight to qbuf/kbuf (was normrope). Numerics identical to
//                the separate-kernel path: acc is rounded to bf16 first (as the
//                old qkvb round-trip did), same butterfly sum order, same
//                table formula for cos/sin.
#define BM 128
#define BN 128
#define BK 64
template <typename OT, bool FUSED>
__global__ __launch_bounds__(256, 3) void gemm_bt(const unsigned short* __restrict__ A,
                                                  const unsigned short* __restrict__ Bm,
                                                  OT* __restrict__ C,
                                                  unsigned short* __restrict__ vtb,
                                                  unsigned short* __restrict__ qbuf,
                                                  unsigned short* __restrict__ kbuf,
                                                  const float* __restrict__ qgain,
                                                  const float* __restrict__ CS,
                                                  const float* __restrict__ SN,
                                                  int M, int N, int K) {
  // FUSED: SH doubles as T2[d][tok] (stride 132) in the norm epilogue (33 KB).
  __shared__ unsigned short SH[FUSED ? 16896 : 16384];
  unsigned short* As = SH;                 // 8192 elems
  unsigned short* Bs = SH + 8192;          // 8192 elems
  const int tid = threadIdx.x;
  const int wave = tid >> 6, lane = tid & 63;
  const int quad = lane >> 4, l16 = lane & 15;

  // XCD bijective swizzle (nwg % 8 == 0 for both launches: 768, 512)
  int wg = blockIdx.y * gridDim.x + blockIdx.x;
  int nwg = gridDim.x * gridDim.y;
  int cpx = nwg >> 3;
  int swz = (wg & 7) * cpx + (wg >> 3);
  int bxs = swz % gridDim.x, bys = swz / gridDim.x;
  const int m0 = bxs * BM, n0 = bys * BN;
  const int wm = (wave >> 1) * 64, wn = (wave & 1) * 64;

  const unsigned short* Ag = A + (size_t)m0 * K;
  const unsigned short* Bg = Bm + (size_t)n0 * K;

  f32x4 acc[4][4];
#pragma unroll
  for (int i = 0; i < 4; i++)
#pragma unroll
    for (int j = 0; j < 4; j++) acc[i][j] = f32x4{0.f, 0.f, 0.f, 0.f};

  // staging: copy c stages rows c*32..c*32+31; thread covers row tid>>3.
  // Source granule pre-swizzled: (lane&7) ^ (row&7), row&7 == lane>>3.
  const int srow = tid >> 3;
  const int sg8 = (((lane & 7) ^ (lane >> 3))) * 8;
  const unsigned short* gA = Ag + (size_t)srow * K + sg8;
  const unsigned short* gB = Bg + (size_t)srow * K + sg8;
  unsigned short* lA = &As[wave * 512];    // wave-uniform; HW scatters lane*16B
  unsigned short* lB = &Bs[wave * 512];

  for (int k0 = 0; k0 < K; k0 += BK) {
    __syncthreads();
#pragma unroll
    for (int c = 0; c < 4; ++c) async_copy16(gA + (size_t)c * 32 * K + k0, lA + c * 2048);
#pragma unroll
    for (int c = 0; c < 4; ++c) async_copy16(gB + (size_t)c * 32 * K + k0, lB + c * 2048);
    __syncthreads();
#pragma unroll
    for (int kk = 0; kk < 2; ++kk) {
      bf16x8 af[4], bf[4];
#pragma unroll
      for (int t = 0; t < 4; t++)
        af[t] = *(const bf16x8*)&As[(wm + t * 16 + l16) * BK + ((((kk << 2) + quad) ^ (l16 & 7)) << 3)];
#pragma unroll
      for (int t = 0; t < 4; t++)
        bf[t] = *(const bf16x8*)&Bs[(wn + t * 16 + l16) * BK + ((((kk << 2) + quad) ^ (l16 & 7)) << 3)];
#pragma unroll
      for (int i = 0; i < 4; i++)
#pragma unroll
        for (int j = 0; j < 4; j++)
          acc[i][j] = __builtin_amdgcn_mfma_f32_16x16x32_bf16(af[i], bf[j], acc[i][j], 0, 0, 0);
    }
  }

  if constexpr (FUSED) {
    if (n0 >= 2560) {
      // ---- V section: transposed store to vtb[((bz*4+kvh)*128+d)*2048+s] ----
      const int kvh = (n0 - 2560) >> 7;
#pragma unroll
      for (int i = 0; i < 4; i++) {
        int row0 = m0 + wm + i * 16 + quad * 4;    // 4 consecutive tokens
        int bz = row0 >> 11, s0 = row0 & 2047;     // tile never crosses bz
#pragma unroll
        for (int j = 0; j < 4; j++) {
          int d = wn + j * 16 + l16;
          u16x4 o;
#pragma unroll
          for (int r = 0; r < 4; r++) o[r] = fto16(acc[i][j][r]);
          *(u16x4*)&vtb[(size_t)((bz * NKV + kvh) * HD + d) * SEQ + s0] = o;
        }
      }
      return;
    }
    // ---- Q/K section: RMSNorm + RoPE (+gain for Q), straight to qbuf/kbuf ----
    __syncthreads();                     // all waves done reading As/Bs
    // stage bf16 C-tile as T2[d][tok], row stride 132 (8B-aligned, ~4-way max)
#pragma unroll
    for (int i = 0; i < 4; i++) {
      int tok0 = wm + i * 16 + quad * 4;
#pragma unroll
      for (int j = 0; j < 4; j++) {
        int d = wn + j * 16 + l16;
        u16x4 w;
#pragma unroll
        for (int r = 0; r < 4; r++) w[r] = fto16(acc[i][j][r]);
        *(u16x4*)&SH[d * 132 + tok0] = w;
      }
    }
    __syncthreads();
    const bool isq = (n0 < 2048);
    const int hh = isq ? (n0 >> 7) : ((n0 - 2048) >> 7);
    const float g = isq ? qgain[hh] * QSCALE : 1.0f;
    // wave handles tokens wave*32..+31 in 8 groups of 4; lane holds d=lane,lane+64
#pragma unroll 1
    for (int gr = 0; gr < 8; ++gr) {
      int tk = wave * 32 + gr * 4;
      u16x4 a = *(const u16x4*)&SH[lane * 132 + tk];
      u16x4 b = *(const u16x4*)&SH[(lane + 64) * 132 + tk];
      float x1[4], x2[4], ss[4];
#pragma unroll
      for (int r = 0; r < 4; r++) {
        x1[r] = b2f(a[r]); x2[r] = b2f(b[r]);
        ss[r] = x1[r] * x1[r] + x2[r] * x2[r];
      }
#pragma unroll
      for (int o = 32; o; o >>= 1)
#pragma unroll
        for (int r = 0; r < 4; r++) ss[r] += __shfl_xor(ss[r], o);
#pragma unroll
      for (int r = 0; r < 4; r++) {
        int gt = m0 + tk + r;
        int bz = gt >> 11, tokg = gt & 2047;
        float rn = rsqrtf(ss[r] * (1.0f / 128.0f) + 1.1920929e-07f);
        float cs = CS[tokg * 64 + lane], sn = SN[tokg * 64 + lane];
        float n1 = x1[r] * rn, n2 = x2[r] * rn;
        unsigned short* dst = isq
            ? qbuf + ((size_t)(bz * NH + hh) * SEQ + tokg) * HD
            : kbuf + ((size_t)(bz * NKV + hh) * SEQ + tokg) * HD;
        dst[lane]      = fto16((n1 * cs + n2 * sn) * g);
        dst[lane + 64] = fto16((-n1 * sn + n2 * cs) * g);
      }
    }
    return;
  }

#pragma unroll
  for (int i = 0; i < 4; i++) {
    int row_base = m0 + wm + i * 16 + quad * 4;
#pragma unroll
    for (int j = 0; j < 4; j++) {
      int col = n0 + wn + j * 16 + l16;
#pragma unroll
      for (int r = 0; r < 4; r++) {
        if constexpr (sizeof(OT) == 2)
          C[(size_t)(row_base + r) * N + col] = fto16(acc[i][j][r]);
        else
          C[(size_t)(row_base + r) * N + col] = acc[i][j][r];
      }
    }
  }
}

// ---------------- flash attention (R3/R7 version, best measured) -------------
// 128-row Q tile, 8 waves (16 rows/wave). K: dbuf direct global_load_lds
// (pre-swizzled global source, linear LDS dest - rule-21 involution); K(kt+1)
// issued between barriers A and B, in flight across compute(kt), drained by the
// next iteration's __syncthreads. V: reg-prefetch + swizzled ds_write.
__global__ __launch_bounds__(512, 4) void attn_kernel(const unsigned short* __restrict__ qb,
                                                      const unsigned short* __restrict__ kb,
                                                      const unsigned short* __restrict__ vtb,
                                                      unsigned short* __restrict__ yb) {
  __shared__ unsigned short Ks[2][64 * 128];  // 32 KB (dbuf)
  __shared__ unsigned short Vt[128 * 64];     // 16 KB
  __shared__ unsigned short Ps[8][16 * 64];   // 16 KB   -> 64 KB total

  const int bx = blockIdx.x;
  const int h = blockIdx.y;
  const int bz = blockIdx.z;
  const int qt = bz ? bx : (15 - bx);     // bz-pairing: CU partner gets 15-qt
  const int tid = threadIdx.x;
  const int wave = tid >> 6, lane = tid & 63;
  const int quad = lane >> 4, l16 = lane & 15;
  const int q0 = qt * 128;
  const int base = q0 + wave * 16;        // this wave's 16-row group
  const int kdiag = base >> 6;

  const unsigned short* qg = qb + (size_t)(bz * NH + h) * SEQ * HD;
  const unsigned short* kg = kb + (size_t)(bz * NKV + (h >> 2)) * SEQ * HD;
  const unsigned short* vg = vtb + (size_t)(bz * NKV + (h >> 2)) * HD * SEQ;
  unsigned short* psw = &Ps[wave][0];

  bf16x8 qf[4];
#pragma unroll
  for (int ds = 0; ds < 4; ++ds)
    qf[ds] = *(const bf16x8*)(qg + (size_t)(base + l16) * HD + ds * 32 + quad * 8);

  f32x4 oacc[8];
#pragma unroll
  for (int j = 0; j < 8; ++j) oacc[j] = f32x4{0.f, 0.f, 0.f, 0.f};
  float m_i = -__builtin_inff();
  float l_i = 0.f;

  const int krow0 = wave * 4 + (lane >> 4);
  const int ksrcg = (lane & 15) ^ (krow0 & 15);
  const unsigned short* kgK = kg + (size_t)krow0 * HD + ksrcg * 8;

  const int vdw = tid >> 3, vgr = tid & 7;    // 64 d/iter, 8 granules/row

  const int nkt = 2 * qt + 2;

  // prologue: stage K(0) direct, prefetch V(0) to regs
  async_copy16(kgK, &Ks[0][wave * 512]);
  async_copy16(kgK + (size_t)32 * HD, &Ks[0][4096 + wave * 512]);
  u16x8 pv[2];
#pragma unroll
  for (int i = 0; i < 2; ++i)
    pv[i] = *(const u16x8*)(vg + (size_t)(i * 64 + vdw) * SEQ + vgr * 8);

  for (int kt = 0; kt < nkt; ++kt) {
    // (A) full drain + barrier: prev LDS reads done, K(kt) DMA landed, pv(kt) ready
    __syncthreads();
#pragma unroll
    for (int i = 0; i < 2; ++i) {
      int d = i * 64 + vdw;
      *(u16x8*)&Vt[d * 64 + ((vgr ^ (d & 7)) << 3)] = pv[i];
    }
    if (kt + 1 < nkt) {                  // stage K(kt+1): flies across compute(kt)
      const unsigned short* s = kgK + (size_t)(kt + 1) * 64 * HD;
      async_copy16(s, &Ks[(kt + 1) & 1][wave * 512]);
      async_copy16(s + (size_t)32 * HD, &Ks[(kt + 1) & 1][4096 + wave * 512]);
    }
    __asm__ volatile("s_waitcnt lgkmcnt(0)" ::: "memory");  // my V writes visible
    __builtin_amdgcn_sched_barrier(0);
    __asm__ volatile("s_barrier" ::: "memory");  // (B) V staged; K(kt+1) in flight

    if (kt + 1 < nkt) {                  // prefetch V(kt+1) into regs
#pragma unroll
      for (int i = 0; i < 2; ++i)
        pv[i] = *(const u16x8*)(vg + (size_t)(i * 64 + vdw) * SEQ + (kt + 1) * 64 + vgr * 8);
    }

    if (kt <= kdiag) {
      const unsigned short* Kc = Ks[kt & 1];
      f32x4 st[4];
#pragma unroll
      for (int mt = 0; mt < 4; ++mt) st[mt] = f32x4{0.f, 0.f, 0.f, 0.f};
      __builtin_amdgcn_s_setprio(1);
#pragma unroll
      for (int mt = 0; mt < 4; ++mt)
#pragma unroll
        for (int ds = 0; ds < 4; ++ds) {
          bf16x8 kf = *(const bf16x8*)&Kc[(mt * 16 + l16) * 128 + ((((ds << 2) + quad) ^ l16) << 3)];
          st[mt] = __builtin_amdgcn_mfma_f32_16x16x32_bf16(kf, qf[ds], st[mt], 0, 0, 0);
        }
      __builtin_amdgcn_s_setprio(0);

      const int qrow = base + l16;
      float p[4][4];
      float mx = -__builtin_inff();
      if (kt == kdiag) {                 // diagonal tile: causal mask
#pragma unroll
        for (int mt = 0; mt < 4; ++mt)
#pragma unroll
          for (int r = 0; r < 4; ++r) {
            int kp = kt * 64 + mt * 16 + quad * 4 + r;
            float v = (kp <= qrow) ? st[mt][r] : -__builtin_inff();
            p[mt][r] = v;
            mx = fmaxf(mx, v);
          }
      } else {
#pragma unroll
        for (int mt = 0; mt < 4; ++mt)
#pragma unroll
          for (int r = 0; r < 4; ++r) {
            p[mt][r] = st[mt][r];
            mx = fmaxf(mx, st[mt][r]);
          }
      }
      mx = fmaxf(mx, __shfl_xor(mx, 16));
      mx = fmaxf(mx, __shfl_xor(mx, 32));
      float mnew = (mx > m_i + 8.f) ? mx : m_i;   // defer-max THR=8
      float rs = 0.f;
#pragma unroll
      for (int mt = 0; mt < 4; ++mt)
#pragma unroll
        for (int r = 0; r < 4; ++r) {
          float e = exp2f(p[mt][r] - mnew);
          p[mt][r] = e;
          rs += e;
        }
      rs += __shfl_xor(rs, 16);
      rs += __shfl_xor(rs, 32);
      if (mnew != m_i) {                 // rescale only when deferred max moved
        float a = exp2f(m_i - mnew);
#pragma unroll
        for (int j = 0; j < 8; ++j) oacc[j] *= a;
        l_i = l_i * a + rs;
        m_i = mnew;
      } else {
        l_i += rs;
      }

#pragma unroll
      for (int mt = 0; mt < 4; ++mt) {
        u16x4 w;
#pragma unroll
        for (int r = 0; r < 4; ++r) w[r] = fto16(p[mt][r]);
        int g = mt * 2 + (quad >> 1);
        *(u16x4*)&psw[l16 * 64 + ((g ^ (l16 & 7)) << 3) + (quad & 1) * 4] = w;
      }

      __asm__ volatile("s_waitcnt lgkmcnt(0)" ::: "memory");  // own P writes -> reads

      __builtin_amdgcn_s_setprio(1);
#pragma unroll
      for (int c = 0; c < 2; ++c) {
        bf16x8 pf = *(const bf16x8*)&psw[l16 * 64 + ((((c << 2) + quad) ^ (l16 & 7)) << 3)];
#pragma unroll
        for (int mt = 0; mt < 8; ++mt) {
          bf16x8 vf = *(const bf16x8*)&Vt[(mt * 16 + l16) * 64 + ((((c << 2) + quad) ^ (l16 & 7)) << 3)];
          oacc[mt] = __builtin_amdgcn_mfma_f32_16x16x32_bf16(vf, pf, oacc[mt], 0, 0, 0);
        }
      }
      __builtin_amdgcn_s_setprio(0);
    }
  }

  // epilogue: O^T row = d = mt*16+quad*4+r, col = q = l16; per-lane invl
  {
    float il = 1.0f / l_i;
    int qrow = base + l16;
#pragma unroll
    for (int mt = 0; mt < 8; ++mt) {
      u16x4 o;
#pragma unroll
      for (int r = 0; r < 4; ++r) o[r] = fto16(oacc[mt][r] * il);
      *(u16x4*)&yb[(size_t)(bz * SEQ + qrow) * DMODEL + h * HD + mt * 16 + quad * 4] = o;
    }
  }
}

extern "C" void kernel_launch(void* const* d_in, const int* in_sizes, int n_in,
                              void* d_out, int out_size, void* d_ws, size_t ws_size,
                              hipStream_t stream) {
  (void)in_sizes; (void)n_in; (void)out_size; (void)ws_size;
  const float* x  = (const float*)d_in[0];
  const float* Wq = (const float*)d_in[1];
  const float* Wk = (const float*)d_in[2];
  const float* Wv = (const float*)d_in[3];
  const float* Wp = (const float*)d_in[4];
  const float* qg = (const float*)d_in[5];
  float* out = (float*)d_out;
  char* ws = (char*)d_ws;

  // workspace layout; yb aliases xb (x consumed by GEMM1 before attn writes y)
  unsigned short* xb   = (unsigned short*)(ws + 0);          // 16.78 MB
  unsigned short* Wcat = (unsigned short*)(ws + 16777216);   // 12.58 MB (Wq|Wk|Wv rows)
  unsigned short* Wpq  = (unsigned short*)(ws + 29360128);   // 8.39 MB
  float*          CS   = (float*)(ws + 37748736);            // 0.52 MB rope cos
  float*          SN   = (float*)(ws + 38273024);            // 0.52 MB rope sin
  unsigned short* qbuf = (unsigned short*)(ws + 62914560);   // 16.78 MB
  unsigned short* kbuf = (unsigned short*)(ws + 79691776);   // 4.19 MB
  unsigned short* vtb  = (unsigned short*)(ws + 83886080);   // 4.19 MB (V^T)
  unsigned short* yb   = xb;

  // prep: fq (20480 blk) + x conv (8192 blk) + rope tables (512 blk)
  prep_kernel<<<NFQ + NCONV + NROPE, 256, 0, stream>>>(Wq, Wk, Wv, Wp, x,
                                                       Wcat, Wpq, xb, CS, SN);
  // gemm1: Q,K -> norm+rope -> qbuf/kbuf; V -> transposed -> vtb (all fused)
  gemm_bt<unsigned short, true><<<dim3(32, 24), 256, 0, stream>>>(
      xb, Wcat, (unsigned short*)nullptr, vtb, qbuf, kbuf, qg, CS, SN,
      MROWS, NTOT, DMODEL);
  attn_kernel<<<dim3(16, NH, 2), 512, 0, stream>>>(qbuf, kbuf, vtb, yb);
  gemm_bt<float, false><<<dim3(32, 16), 256, 0, stream>>>(
      yb, Wpq, out, nullptr, nullptr, nullptr, nullptr, nullptr, nullptr,
      MROWS, DMODEL, DMODEL);
}